// Round 9
// baseline (248.183 us; speedup 1.0000x reference)
//
#include <hip/hip_runtime.h>
#include <math.h>

#define TEMP_INV 10.0f
#define MASKV -1.0f
#define EPSV 1e-12f
#define GAP 2e-3f

typedef __attribute__((ext_vector_type(8))) short bf16x8;
typedef __attribute__((ext_vector_type(4))) float f32x4;

#define RL(v, l) __uint_as_float(__builtin_amdgcn_readlane(__float_as_uint(v), (l)))

__device__ __forceinline__ float wmax(float v) {
#pragma unroll
  for (int m = 1; m < 64; m <<= 1) v = fmaxf(v, __shfl_xor(v, m));
  return v;
}
__device__ __forceinline__ float wsum(float v) {
#pragma unroll
  for (int m = 1; m < 64; m <<= 1) v += __shfl_xor(v, m);
  return v;
}

__device__ __forceinline__ unsigned short rne_bf16(float x) {
  unsigned u = __float_as_uint(x);
  return (unsigned short)((u + 0x7FFF + ((u >> 16) & 1)) >> 16);
}

#define DOT4(accv, Av, Bv)       \
  accv = fmaf(Av.x, Bv.x, accv); \
  accv = fmaf(Av.y, Bv.y, accv); \
  accv = fmaf(Av.z, Bv.z, accv); \
  accv = fmaf(Av.w, Bv.w, accv);

// ---------------------------------------------------------------------------
// Kernel 0: w1t[256][512] = W1[512][256]^T  (LDS-tiled transpose, into d_out)
// ---------------------------------------------------------------------------
__global__ __launch_bounds__(256) void k_tr(const float* __restrict__ W1,
                                            float* __restrict__ w1t) {
  __shared__ float tile[32][33];
  int bx = blockIdx.x;  // c-tile (8)
  int by = blockIdx.y;  // d-tile (16)
  int t = threadIdx.x;
  int tr = t >> 5, tc = t & 31;
#pragma unroll
  for (int p = 0; p < 4; ++p) {
    int d = by * 32 + p * 8 + tr;
    int c = bx * 32 + tc;
    tile[p * 8 + tr][tc] = W1[d * 256 + c];
  }
  __syncthreads();
#pragma unroll
  for (int p = 0; p < 4; ++p) {
    int c = bx * 32 + p * 8 + tr;  // output row (W1 column)
    int d = by * 32 + tc;          // output col
    w1t[c * 512 + d] = tile[tc][p * 8 + tr];
  }
}

// ---------------------------------------------------------------------------
// Kernel 1: Gram matrices G[j][w][w'] = caps[j,w].caps[j,w'], stride-52 rows
// ---------------------------------------------------------------------------
__global__ __launch_bounds__(128) void k_gram(const float* __restrict__ caps,
                                              float* __restrict__ G) {
  int j = blockIdx.y, h = blockIdx.x;
  int t = threadIdx.x;
  __shared__ __align__(16) float cs[52 * 128];

  int rg = t / 13, wg = t - rg * 13;
  bool act = (t < 91);
  int r0 = h * 24 + 4 * rg;
  int w0 = 4 * wg;
  int fa = (r0 >> 2) & 7;
  int fb = wg & 7;
  float acc[4][4] = {};

  for (int ch = 0; ch < 4; ++ch) {
    int d0 = ch * 128;
    for (int ps = 0; ps < 13; ++ps) {
      int row = ps * 4 + (t >> 5);
      int c = t & 31;
      int grow = row > 49 ? 49 : row;
      float4 v = *(const float4*)&caps[(j * 50 + grow) * 512 + d0 + c * 4];
      *(float4*)&cs[row * 128 + ((c ^ (ps & 7)) << 2)] = v;
    }
    __syncthreads();
    if (act) {
      const float* aB = &cs[r0 * 128];
      const float* bB = &cs[w0 * 128];
#pragma unroll
      for (int q = 0; q < 32; ++q) {
        int pa = ((q ^ fa) << 2), pb = ((q ^ fb) << 2);
        float4 A0 = *(const float4*)(aB + pa);
        float4 A1 = *(const float4*)(aB + 128 + pa);
        float4 A2 = *(const float4*)(aB + 256 + pa);
        float4 A3 = *(const float4*)(aB + 384 + pa);
        float4 B0 = *(const float4*)(bB + pb);
        float4 B1 = *(const float4*)(bB + 128 + pb);
        float4 B2 = *(const float4*)(bB + 256 + pb);
        float4 B3 = *(const float4*)(bB + 384 + pb);
        DOT4(acc[0][0], A0, B0) DOT4(acc[0][1], A0, B1)
        DOT4(acc[0][2], A0, B2) DOT4(acc[0][3], A0, B3)
        DOT4(acc[1][0], A1, B0) DOT4(acc[1][1], A1, B1)
        DOT4(acc[1][2], A1, B2) DOT4(acc[1][3], A1, B3)
        DOT4(acc[2][0], A2, B0) DOT4(acc[2][1], A2, B1)
        DOT4(acc[2][2], A2, B2) DOT4(acc[2][3], A2, B3)
        DOT4(acc[3][0], A3, B0) DOT4(acc[3][1], A3, B1)
        DOT4(acc[3][2], A3, B2) DOT4(acc[3][3], A3, B3)
      }
    }
    __syncthreads();
  }
  if (act) {
#pragma unroll
    for (int p = 0; p < 4; ++p) {
      int w = r0 + p;
      if (w < 50) {
#pragma unroll
        for (int qq = 0; qq < 4; ++qq) {
          int wp = w0 + qq;
          if (wp < 50) G[j * 2600 + w * 52 + wp] = acc[p][qq];
        }
      }
    }
  }
}

// ---------------------------------------------------------------------------
// Kernel 2: sims+h via MFMA bf16x3 split GEMM.
// C[2304][3456] = imgs · [caps; W1^T]^T, K=512. Block 128×128, 4 waves,
// wave = 4×4 of 16×16×32 mfma tiles. 3-term: ah·bh + ah·bl + al·bh.
// ---------------------------------------------------------------------------
__global__ __launch_bounds__(256, 2) void k_sims(const float* __restrict__ imgs,
                                                 const float* __restrict__ caps,
                                                 const float* __restrict__ w1t,
                                                 float* __restrict__ sims) {
  __shared__ __align__(16) short AH[128 * 64];
  __shared__ __align__(16) short AL[128 * 64];
  __shared__ __align__(16) short BH[128 * 64];
  __shared__ __align__(16) short BL[128 * 64];

  int bid = blockIdx.x;
  int bm = bid / 27, bn = bid - bm * 27;
  int t = threadIdx.x, lane = t & 63, wv = t >> 6;

  int wm = wv >> 1, wn = wv & 1;
  int frow = lane & 15, fk = lane >> 4;
  int sw = frow & 7;

  int srow = t >> 3, sq = t & 7;
  const float* aBase = imgs + (size_t)(bm * 128 + srow) * 512 + 8 * sq;
  const float* Bm = (bn < 25) ? caps + (size_t)bn * 128 * 512
                              : w1t + (size_t)(bn - 25) * 128 * 512;
  const float* bBase = Bm + (size_t)srow * 512 + 8 * sq;

  f32x4 acc[4][4] = {};

  for (int kc = 0; kc < 8; ++kc) {
#pragma unroll
    for (int ii = 0; ii < 4; ++ii) {
      int row = ii * 32 + srow;
      int sp = ((sq ^ (row & 7)) << 3) + row * 64;
      {
        const float* p = aBase + (size_t)(ii * 32) * 512 + kc * 64;
        float4 x0 = *(const float4*)p;
        float4 x1 = *(const float4*)(p + 4);
        float xs[8] = {x0.x, x0.y, x0.z, x0.w, x1.x, x1.y, x1.z, x1.w};
        bf16x8 hi, lo;
#pragma unroll
        for (int e = 0; e < 8; ++e) {
          unsigned short hb = rne_bf16(xs[e]);
          float hf = __uint_as_float((unsigned)hb << 16);
          hi[e] = (short)hb;
          lo[e] = (short)rne_bf16(xs[e] - hf);
        }
        *(bf16x8*)&AH[sp] = hi;
        *(bf16x8*)&AL[sp] = lo;
      }
      {
        const float* p = bBase + (size_t)(ii * 32) * 512 + kc * 64;
        float4 x0 = *(const float4*)p;
        float4 x1 = *(const float4*)(p + 4);
        float xs[8] = {x0.x, x0.y, x0.z, x0.w, x1.x, x1.y, x1.z, x1.w};
        bf16x8 hi, lo;
#pragma unroll
        for (int e = 0; e < 8; ++e) {
          unsigned short hb = rne_bf16(xs[e]);
          float hf = __uint_as_float((unsigned)hb << 16);
          hi[e] = (short)hb;
          lo[e] = (short)rne_bf16(xs[e] - hf);
        }
        *(bf16x8*)&BH[sp] = hi;
        *(bf16x8*)&BL[sp] = lo;
      }
    }
    __syncthreads();

#pragma unroll
    for (int ks = 0; ks < 2; ++ks) {
      int slot = (ks << 2) | fk;
      bf16x8 bh[4], bl[4];
#pragma unroll
      for (int nt = 0; nt < 4; ++nt) {
        int br = wn * 64 + nt * 16 + frow;
        int off = br * 64 + ((slot ^ sw) << 3);
        bh[nt] = *(const bf16x8*)&BH[off];
        bl[nt] = *(const bf16x8*)&BL[off];
      }
#pragma unroll
      for (int mt = 0; mt < 4; ++mt) {
        int ar = wm * 64 + mt * 16 + frow;
        int off = ar * 64 + ((slot ^ sw) << 3);
        bf16x8 ah = *(const bf16x8*)&AH[off];
        bf16x8 al = *(const bf16x8*)&AL[off];
#pragma unroll
        for (int nt = 0; nt < 4; ++nt) {
          acc[mt][nt] = __builtin_amdgcn_mfma_f32_16x16x32_bf16(
              ah, bh[nt], acc[mt][nt], 0, 0, 0);
          acc[mt][nt] = __builtin_amdgcn_mfma_f32_16x16x32_bf16(
              ah, bl[nt], acc[mt][nt], 0, 0, 0);
          acc[mt][nt] = __builtin_amdgcn_mfma_f32_16x16x32_bf16(
              al, bh[nt], acc[mt][nt], 0, 0, 0);
        }
      }
    }
    __syncthreads();
  }

#pragma unroll
  for (int mt = 0; mt < 4; ++mt) {
#pragma unroll
    for (int nt = 0; nt < 4; ++nt) {
      int grow0 = bm * 128 + wm * 64 + mt * 16 + fk * 4;
      int gcol = bn * 128 + wn * 64 + nt * 16 + frow;
#pragma unroll
      for (int v = 0; v < 4; ++v)
        sims[(size_t)(grow0 + v) * 3456 + gcol] = acc[mt][nt][v];
    }
  }
}

// ---------------------------------------------------------------------------
// Kernel 3: unc = sigmoid(relu(h+b1)@W2 + b2); nrm = ||imgs_row||.
// Wave per row; h read from sims columns 3200..3455.
// ---------------------------------------------------------------------------
__global__ __launch_bounds__(256) void k_unc(
    const float* __restrict__ sims, const float* __restrict__ imgs,
    const float* __restrict__ b1, const float* __restrict__ W2,
    const float* __restrict__ b2, float* __restrict__ unc,
    float* __restrict__ nrm) {
  int t = threadIdx.x, lane = t & 63, wv = t >> 6;
  int r = blockIdx.x * 4 + wv;
  float4 h4 = *(const float4*)&sims[(size_t)r * 3456 + 3200 + lane * 4];
  float4 b4 = *(const float4*)&b1[lane * 4];
  float4 w4 = *(const float4*)&W2[lane * 4];
  float a = 0.f;
  a = fmaf(fmaxf(h4.x + b4.x, 0.f), w4.x, a);
  a = fmaf(fmaxf(h4.y + b4.y, 0.f), w4.y, a);
  a = fmaf(fmaxf(h4.z + b4.z, 0.f), w4.z, a);
  a = fmaf(fmaxf(h4.w + b4.w, 0.f), w4.w, a);
  const float* ir = imgs + (size_t)r * 512 + lane * 8;
  float4 x0 = *(const float4*)ir;
  float4 x1 = *(const float4*)(ir + 4);
  float n = x0.x * x0.x + x0.y * x0.y + x0.z * x0.z + x0.w * x0.w +
            x1.x * x1.x + x1.y * x1.y + x1.z * x1.z + x1.w * x1.w;
  a = wsum(a);
  n = wsum(n);
  if (lane == 0) {
    unc[r] = 1.f / (1.f + __expf(-(a + b2[0])));
    nrm[r] = sqrtf(n);
  }
}

// ---------------------------------------------------------------------------
// Kernel 4: attention epilogue. One wave per (i,j,r); zero LDS, zero barriers.
// G row (padded stride 52) in 52 VGPRs per lane; Gp via readlane chain.
// ---------------------------------------------------------------------------
__global__ __launch_bounds__(256) void k_attn(
    const float* __restrict__ sims, const float* __restrict__ G,
    const float* __restrict__ unc, const float* __restrict__ nrm,
    const int* __restrict__ img_lens, const int* __restrict__ cap_lens,
    const float* __restrict__ imgs, const float* __restrict__ caps,
    float* __restrict__ out) {
  int rq = blockIdx.x, j = blockIdx.y, i = blockIdx.z;
  int t = threadIdx.x, lane = t & 63, wv = t >> 6;
  int r = rq * 4 + wv;

  const float* gb = G + j * 2600 + (lane < 50 ? lane : 49) * 52;
  float4 g4[13];
#pragma unroll
  for (int k = 0; k < 13; ++k) g4[k] = *(const float4*)(gb + 4 * k);

  int ilen = img_lens[i];
  int cl = cap_lens[j];
  cl = cl > 50 ? 50 : cl;

  float s = (lane < 50) ? sims[(size_t)(i * 36 + r) * 3456 + j * 50 + lane] : 0.f;
  bool valid = lane < cl;
  float sv = valid ? s : -INFINITY;
  float m = wmax(sv);
  bool cand = valid && (sv >= m - GAP);
  unsigned long long nearmask = __ballot(cand);
  int fl;
  if (__popcll(nearmask) <= 1) {
    fl = (int)__ffsll(nearmask) - 1;
  } else {
    float ex = -INFINITY;
    if (cand) {
      const float* ar = imgs + (size_t)(i * 36 + r) * 512;
      const float* br = caps + (size_t)(j * 50 + lane) * 512;
      float4 a4 = make_float4(0.f, 0.f, 0.f, 0.f);
      for (int k = 0; k < 512; k += 4) {
        float4 av = *(const float4*)(ar + k);
        float4 bv = *(const float4*)(br + k);
        a4.x = fmaf(av.x, bv.x, a4.x);
        a4.y = fmaf(av.y, bv.y, a4.y);
        a4.z = fmaf(av.z, bv.z, a4.z);
        a4.w = fmaf(av.w, bv.w, a4.w);
      }
      ex = (a4.x + a4.y) + (a4.z + a4.w);
    }
    float mex = wmax(ex);
    fl = (int)__ffsll(__ballot(ex == mex)) - 1;
  }
  float e = valid ? __expf((sv - m) * TEMP_INV) : 0.f;
  float dn = wsum(e);
  float alpha = unc[i * 36 + r];
  float p = alpha * e / dn;
  if (m > MASKV && lane == fl) p += (1.f - alpha);
  float num = wsum(valid ? p * s : 0.f);

  float gp0 = 0.f, gp1 = 0.f, gp2 = 0.f, gp3 = 0.f;
#pragma unroll
  for (int k = 0; k < 12; ++k) {
    int wp = 4 * k;
    gp0 = fmaf(RL(p, wp), g4[k].x, gp0);
    gp1 = fmaf(RL(p, wp + 1), g4[k].y, gp1);
    gp2 = fmaf(RL(p, wp + 2), g4[k].z, gp2);
    gp3 = fmaf(RL(p, wp + 3), g4[k].w, gp3);
  }
  gp0 = fmaf(RL(p, 48), g4[12].x, gp0);
  gp1 = fmaf(RL(p, 49), g4[12].y, gp1);
  float gp = (gp0 + gp1) + (gp2 + gp3);
  float qd = wsum(p * gp);
  if (lane == 0) {
    float res = MASKV;
    if (r < ilen) {
      float ni = fmaxf(nrm[i * 36 + r], EPSV);
      float nw = fmaxf(sqrtf(qd), EPSV);
      res = num / (ni * nw);
    }
    out[(i * 64 + j) * 36 + r] = res;
  }
}

extern "C" void kernel_launch(void* const* d_in, const int* in_sizes, int n_in,
                              void* d_out, int out_size, void* d_ws,
                              size_t ws_size, hipStream_t stream) {
  const float* imgs = (const float*)d_in[0];
  const float* caps = (const float*)d_in[1];
  const int* img_lens = (const int*)d_in[2];
  const int* cap_lens = (const int*)d_in[3];
  const float* W1 = (const float*)d_in[4];
  const float* b1 = (const float*)d_in[5];
  const float* W2 = (const float*)d_in[6];
  const float* b2 = (const float*)d_in[7];
  float* out = (float*)d_out;
  float* ws = (float*)d_ws;
  float* unc = ws;            // 2304 floats
  float* nrm = ws + 2304;     // 2304 floats
  float* G = ws + 4608;       // 64*2600 = 166400 floats (padded stride 52)
  float* sims = ws + 171008;  // 2304*3456 = 7,962,624 floats (~31.9 MB)
  float* w1t = out;           // 131072 floats scratch in d_out; k_attn
                              // fully overwrites out afterwards (stream-ordered)

  hipLaunchKernelGGL(k_tr, dim3(8, 16), dim3(256), 0, stream, W1, w1t);
  hipLaunchKernelGGL(k_gram, dim3(2, 64), dim3(128), 0, stream, caps, G);
  hipLaunchKernelGGL(k_sims, dim3(486), dim3(256), 0, stream, imgs, caps, w1t,
                     sims);
  hipLaunchKernelGGL(k_unc, dim3(576), dim3(256), 0, stream, sims, imgs, b1,
                     W2, b2, unc, nrm);
  hipLaunchKernelGGL(k_attn, dim3(9, 64, 64), dim3(256), 0, stream, sims, G,
                     unc, nrm, img_lens, cap_lens, imgs, caps, out);
}

// Round 10
// 216.065 us; speedup vs baseline: 1.1487x; 1.1487x over previous
//
#include <hip/hip_runtime.h>
#include <math.h>

#define TEMP_INV 10.0f
#define MASKV -1.0f
#define EPSV 1e-12f
#define GAP 2e-3f

typedef __attribute__((ext_vector_type(8))) short bf16x8;
typedef __attribute__((ext_vector_type(4))) float f32x4;

#define RL(v, l) __uint_as_float(__builtin_amdgcn_readlane(__float_as_uint(v), (l)))

__device__ __forceinline__ float wmax(float v) {
#pragma unroll
  for (int m = 1; m < 64; m <<= 1) v = fmaxf(v, __shfl_xor(v, m));
  return v;
}
__device__ __forceinline__ float wsum(float v) {
#pragma unroll
  for (int m = 1; m < 64; m <<= 1) v += __shfl_xor(v, m);
  return v;
}

__device__ __forceinline__ unsigned short rne_bf16(float x) {
  unsigned u = __float_as_uint(x);
  return (unsigned short)((u + 0x7FFF + ((u >> 16) & 1)) >> 16);
}

// ---------------------------------------------------------------------------
// Kernel 0: w1t[256][512] = W1[512][256]^T  (LDS-tiled transpose, into d_out)
// ---------------------------------------------------------------------------
__global__ __launch_bounds__(256) void k_tr(const float* __restrict__ W1,
                                            float* __restrict__ w1t) {
  __shared__ float tile[32][33];
  int bx = blockIdx.x;
  int by = blockIdx.y;
  int t = threadIdx.x;
  int tr = t >> 5, tc = t & 31;
#pragma unroll
  for (int p = 0; p < 4; ++p) {
    int d = by * 32 + p * 8 + tr;
    int c = bx * 32 + tc;
    tile[p * 8 + tr][tc] = W1[d * 256 + c];
  }
  __syncthreads();
#pragma unroll
  for (int p = 0; p < 4; ++p) {
    int c = bx * 32 + p * 8 + tr;
    int d = by * 32 + tc;
    w1t[c * 512 + d] = tile[tc][p * 8 + tr];
  }
}

// ---------------------------------------------------------------------------
// Kernel 1: Gram via MFMA bf16x3. One block per j. M=N=64 (rows>=50 zero),
// K=512. Symmetric: one LDS hi/lo tile serves both A and B operands.
// Output G[j][w][w'] at row stride 56, pad cols 50..55 zeroed.
// ---------------------------------------------------------------------------
__global__ __launch_bounds__(256) void k_gram(const float* __restrict__ caps,
                                              float* __restrict__ G) {
  __shared__ __align__(16) short AH[64 * 64];
  __shared__ __align__(16) short AL[64 * 64];
  int j = blockIdx.x;
  int t = threadIdx.x, lane = t & 63, wv = t >> 6;
  int frow = lane & 15, fk = lane >> 4, sw = frow & 7;
  int srow2 = t >> 3, sq = t & 7;

  f32x4 acc[4] = {};

  for (int kc = 0; kc < 8; ++kc) {
    __syncthreads();
#pragma unroll
    for (int it = 0; it < 2; ++it) {
      int row = it * 32 + srow2;
      int sp = ((sq ^ (row & 7)) << 3) + row * 64;
      bf16x8 hi = {}, lo = {};
      if (row < 50) {
        const float* p = caps + ((size_t)j * 50 + row) * 512 + kc * 64 + 8 * sq;
        float4 x0 = *(const float4*)p;
        float4 x1 = *(const float4*)(p + 4);
        float xs[8] = {x0.x, x0.y, x0.z, x0.w, x1.x, x1.y, x1.z, x1.w};
#pragma unroll
        for (int e = 0; e < 8; ++e) {
          unsigned short hb = rne_bf16(xs[e]);
          float hf = __uint_as_float((unsigned)hb << 16);
          hi[e] = (short)hb;
          lo[e] = (short)rne_bf16(xs[e] - hf);
        }
      }
      *(bf16x8*)&AH[sp] = hi;
      *(bf16x8*)&AL[sp] = lo;
    }
    __syncthreads();
#pragma unroll
    for (int ks = 0; ks < 2; ++ks) {
      int slot = (ks << 2) | fk;
      int ar = wv * 16 + frow;
      int aoff = ar * 64 + ((slot ^ sw) << 3);
      bf16x8 ah = *(const bf16x8*)&AH[aoff];
      bf16x8 al = *(const bf16x8*)&AL[aoff];
#pragma unroll
      for (int nt = 0; nt < 4; ++nt) {
        int br = nt * 16 + frow;
        int boff = br * 64 + ((slot ^ sw) << 3);
        bf16x8 bh = *(const bf16x8*)&AH[boff];
        bf16x8 bl = *(const bf16x8*)&AL[boff];
        acc[nt] = __builtin_amdgcn_mfma_f32_16x16x32_bf16(ah, bh, acc[nt], 0, 0, 0);
        acc[nt] = __builtin_amdgcn_mfma_f32_16x16x32_bf16(ah, bl, acc[nt], 0, 0, 0);
        acc[nt] = __builtin_amdgcn_mfma_f32_16x16x32_bf16(al, bh, acc[nt], 0, 0, 0);
      }
    }
  }
#pragma unroll
  for (int nt = 0; nt < 4; ++nt) {
#pragma unroll
    for (int v = 0; v < 4; ++v) {
      int w = wv * 16 + fk * 4 + v;
      int wp = nt * 16 + frow;
      if (w < 50) {
        if (wp < 50)
          G[(size_t)j * 2800 + w * 56 + wp] = acc[nt][v];
        else if (wp < 56)
          G[(size_t)j * 2800 + w * 56 + wp] = 0.f;  // zero pad (poison guard)
      }
    }
  }
}

// ---------------------------------------------------------------------------
// Kernel 2: sims+h via MFMA bf16x3 split GEMM.
// C[2304][3456] = imgs · [caps; W1^T]^T, K=512. Block 128×128, 4 waves.
// ---------------------------------------------------------------------------
__global__ __launch_bounds__(256, 2) void k_sims(const float* __restrict__ imgs,
                                                 const float* __restrict__ caps,
                                                 const float* __restrict__ w1t,
                                                 float* __restrict__ sims) {
  __shared__ __align__(16) short AH[128 * 64];
  __shared__ __align__(16) short AL[128 * 64];
  __shared__ __align__(16) short BH[128 * 64];
  __shared__ __align__(16) short BL[128 * 64];

  int bid = blockIdx.x;
  int bm = bid / 27, bn = bid - bm * 27;
  int t = threadIdx.x, lane = t & 63, wv = t >> 6;

  int wm = wv >> 1, wn = wv & 1;
  int frow = lane & 15, fk = lane >> 4;
  int sw = frow & 7;

  int srow = t >> 3, sq = t & 7;
  const float* aBase = imgs + (size_t)(bm * 128 + srow) * 512 + 8 * sq;
  const float* Bm = (bn < 25) ? caps + (size_t)bn * 128 * 512
                              : w1t + (size_t)(bn - 25) * 128 * 512;
  const float* bBase = Bm + (size_t)srow * 512 + 8 * sq;

  f32x4 acc[4][4] = {};

  for (int kc = 0; kc < 8; ++kc) {
#pragma unroll
    for (int ii = 0; ii < 4; ++ii) {
      int row = ii * 32 + srow;
      int sp = ((sq ^ (row & 7)) << 3) + row * 64;
      {
        const float* p = aBase + (size_t)(ii * 32) * 512 + kc * 64;
        float4 x0 = *(const float4*)p;
        float4 x1 = *(const float4*)(p + 4);
        float xs[8] = {x0.x, x0.y, x0.z, x0.w, x1.x, x1.y, x1.z, x1.w};
        bf16x8 hi, lo;
#pragma unroll
        for (int e = 0; e < 8; ++e) {
          unsigned short hb = rne_bf16(xs[e]);
          float hf = __uint_as_float((unsigned)hb << 16);
          hi[e] = (short)hb;
          lo[e] = (short)rne_bf16(xs[e] - hf);
        }
        *(bf16x8*)&AH[sp] = hi;
        *(bf16x8*)&AL[sp] = lo;
      }
      {
        const float* p = bBase + (size_t)(ii * 32) * 512 + kc * 64;
        float4 x0 = *(const float4*)p;
        float4 x1 = *(const float4*)(p + 4);
        float xs[8] = {x0.x, x0.y, x0.z, x0.w, x1.x, x1.y, x1.z, x1.w};
        bf16x8 hi, lo;
#pragma unroll
        for (int e = 0; e < 8; ++e) {
          unsigned short hb = rne_bf16(xs[e]);
          float hf = __uint_as_float((unsigned)hb << 16);
          hi[e] = (short)hb;
          lo[e] = (short)rne_bf16(xs[e] - hf);
        }
        *(bf16x8*)&BH[sp] = hi;
        *(bf16x8*)&BL[sp] = lo;
      }
    }
    __syncthreads();

#pragma unroll
    for (int ks = 0; ks < 2; ++ks) {
      int slot = (ks << 2) | fk;
      bf16x8 bh[4], bl[4];
#pragma unroll
      for (int nt = 0; nt < 4; ++nt) {
        int br = wn * 64 + nt * 16 + frow;
        int off = br * 64 + ((slot ^ sw) << 3);
        bh[nt] = *(const bf16x8*)&BH[off];
        bl[nt] = *(const bf16x8*)&BL[off];
      }
#pragma unroll
      for (int mt = 0; mt < 4; ++mt) {
        int ar = wm * 64 + mt * 16 + frow;
        int off = ar * 64 + ((slot ^ sw) << 3);
        bf16x8 ah = *(const bf16x8*)&AH[off];
        bf16x8 al = *(const bf16x8*)&AL[off];
#pragma unroll
        for (int nt = 0; nt < 4; ++nt) {
          acc[mt][nt] = __builtin_amdgcn_mfma_f32_16x16x32_bf16(
              ah, bh[nt], acc[mt][nt], 0, 0, 0);
          acc[mt][nt] = __builtin_amdgcn_mfma_f32_16x16x32_bf16(
              ah, bl[nt], acc[mt][nt], 0, 0, 0);
          acc[mt][nt] = __builtin_amdgcn_mfma_f32_16x16x32_bf16(
              al, bh[nt], acc[mt][nt], 0, 0, 0);
        }
      }
    }
    __syncthreads();
  }

#pragma unroll
  for (int mt = 0; mt < 4; ++mt) {
#pragma unroll
    for (int nt = 0; nt < 4; ++nt) {
      int grow0 = bm * 128 + wm * 64 + mt * 16 + fk * 4;
      int gcol = bn * 128 + wn * 64 + nt * 16 + frow;
#pragma unroll
      for (int v = 0; v < 4; ++v)
        sims[(size_t)(grow0 + v) * 3456 + gcol] = acc[mt][nt][v];
    }
  }
}

// ---------------------------------------------------------------------------
// Kernel 3: unc = sigmoid(relu(h+b1)@W2 + b2); nrm = ||imgs_row||.
// ---------------------------------------------------------------------------
__global__ __launch_bounds__(256) void k_unc(
    const float* __restrict__ sims, const float* __restrict__ imgs,
    const float* __restrict__ b1, const float* __restrict__ W2,
    const float* __restrict__ b2, float* __restrict__ unc,
    float* __restrict__ nrm) {
  int t = threadIdx.x, lane = t & 63, wv = t >> 6;
  int r = blockIdx.x * 4 + wv;
  float4 h4 = *(const float4*)&sims[(size_t)r * 3456 + 3200 + lane * 4];
  float4 b4 = *(const float4*)&b1[lane * 4];
  float4 w4 = *(const float4*)&W2[lane * 4];
  float a = 0.f;
  a = fmaf(fmaxf(h4.x + b4.x, 0.f), w4.x, a);
  a = fmaf(fmaxf(h4.y + b4.y, 0.f), w4.y, a);
  a = fmaf(fmaxf(h4.z + b4.z, 0.f), w4.z, a);
  a = fmaf(fmaxf(h4.w + b4.w, 0.f), w4.w, a);
  const float* ir = imgs + (size_t)r * 512 + lane * 8;
  float4 x0 = *(const float4*)ir;
  float4 x1 = *(const float4*)(ir + 4);
  float n = x0.x * x0.x + x0.y * x0.y + x0.z * x0.z + x0.w * x0.w +
            x1.x * x1.x + x1.y * x1.y + x1.z * x1.z + x1.w * x1.w;
  a = wsum(a);
  n = wsum(n);
  if (lane == 0) {
    unc[r] = 1.f / (1.f + __expf(-(a + b2[0])));
    nrm[r] = sqrtf(n);
  }
}

// ---------------------------------------------------------------------------
// Kernel 4: attention epilogue. Block per (i,j), 8 waves; G staged once to
// LDS (contiguous stride-56 copy); greg as 13 aligned b128/lane; rows
// processed in pairs for 2-way ILP; gp via 8 accumulator chains.
// ---------------------------------------------------------------------------
__global__ __launch_bounds__(512) void k_attn(
    const float* __restrict__ sims, const float* __restrict__ G,
    const float* __restrict__ unc, const float* __restrict__ nrm,
    const int* __restrict__ img_lens, const int* __restrict__ cap_lens,
    const float* __restrict__ imgs, const float* __restrict__ caps,
    float* __restrict__ out) {
  __shared__ __align__(16) float g_s[2800];
  int bid = blockIdx.x;
  int i = bid >> 6, j = bid & 63;
  int t = threadIdx.x, lane = t & 63, wv = t >> 6;

  // stage G_j: contiguous copy, coalesced
  for (int q = t; q < 700; q += 512)
    *(float4*)&g_s[q * 4] = *(const float4*)&G[(size_t)j * 2800 + q * 4];
  __syncthreads();

  int grow = lane < 50 ? lane : 49;
  float4 g4[13];
#pragma unroll
  for (int k = 0; k < 13; ++k)
    g4[k] = *(const float4*)&g_s[grow * 56 + 4 * k];

  int ilen = img_lens[i];
  int cl = cap_lens[j];
  cl = cl > 50 ? 50 : cl;
  bool valid = lane < cl;

  auto prow = [&](int r, bool doStore) {
    float s = (lane < 50) ? sims[(size_t)(i * 36 + r) * 3456 + j * 50 + lane]
                          : 0.f;
    float sv = valid ? s : -INFINITY;
    float m = wmax(sv);
    bool cand = valid && (sv >= m - GAP);
    unsigned long long nearmask = __ballot(cand);
    int fl;
    if (__popcll(nearmask) <= 1) {
      fl = (int)__ffsll(nearmask) - 1;
    } else {
      float ex = -INFINITY;
      if (cand) {
        const float* ar = imgs + (size_t)(i * 36 + r) * 512;
        const float* br = caps + (size_t)(j * 50 + lane) * 512;
        float4 a4 = make_float4(0.f, 0.f, 0.f, 0.f);
        for (int k = 0; k < 512; k += 4) {
          float4 av = *(const float4*)(ar + k);
          float4 bv = *(const float4*)(br + k);
          a4.x = fmaf(av.x, bv.x, a4.x);
          a4.y = fmaf(av.y, bv.y, a4.y);
          a4.z = fmaf(av.z, bv.z, a4.z);
          a4.w = fmaf(av.w, bv.w, a4.w);
        }
        ex = (a4.x + a4.y) + (a4.z + a4.w);
      }
      float mex = wmax(ex);
      fl = (int)__ffsll(__ballot(ex == mex)) - 1;
    }
    float e = valid ? __expf((sv - m) * TEMP_INV) : 0.f;
    float dn = wsum(e);
    float alpha = unc[i * 36 + r];
    float p = alpha * e / dn;
    if (m > MASKV && lane == fl) p += (1.f - alpha);
    float num = wsum(valid ? p * s : 0.f);

    float gp[8] = {};
#pragma unroll
    for (int k = 0; k < 12; ++k) {
      int w = 4 * k;
      int b = (k & 1) << 2;
      gp[b + 0] = fmaf(RL(p, w + 0), g4[k].x, gp[b + 0]);
      gp[b + 1] = fmaf(RL(p, w + 1), g4[k].y, gp[b + 1]);
      gp[b + 2] = fmaf(RL(p, w + 2), g4[k].z, gp[b + 2]);
      gp[b + 3] = fmaf(RL(p, w + 3), g4[k].w, gp[b + 3]);
    }
    gp[0] = fmaf(RL(p, 48), g4[12].x, gp[0]);
    gp[1] = fmaf(RL(p, 49), g4[12].y, gp[1]);
    float gpt = ((gp[0] + gp[4]) + (gp[1] + gp[5])) +
                ((gp[2] + gp[6]) + (gp[3] + gp[7]));
    float qd = wsum(p * gpt);
    if (lane == 0 && doStore) {
      float res = MASKV;
      if (r < ilen) {
        float ni = fmaxf(nrm[i * 36 + r], EPSV);
        float nw = fmaxf(sqrtf(qd), EPSV);
        res = num / (ni * nw);
      }
      out[(i * 64 + j) * 36 + r] = res;
    }
  };

  int nk = (wv < 4) ? 5 : 4;  // rows r = wv + 8k
  for (int k = 0; k < nk; k += 2) {
    bool hasB = (k + 1) < nk;
    int rA = wv + 8 * k;
    int rB = hasB ? (wv + 8 * (k + 1)) : rA;
    prow(rA, true);
    prow(rB, hasB);
  }
}

extern "C" void kernel_launch(void* const* d_in, const int* in_sizes, int n_in,
                              void* d_out, int out_size, void* d_ws,
                              size_t ws_size, hipStream_t stream) {
  const float* imgs = (const float*)d_in[0];
  const float* caps = (const float*)d_in[1];
  const int* img_lens = (const int*)d_in[2];
  const int* cap_lens = (const int*)d_in[3];
  const float* W1 = (const float*)d_in[4];
  const float* b1 = (const float*)d_in[5];
  const float* W2 = (const float*)d_in[6];
  const float* b2 = (const float*)d_in[7];
  float* out = (float*)d_out;
  float* ws = (float*)d_ws;
  float* unc = ws;            // 2304 floats
  float* nrm = ws + 2304;     // 2304 floats
  float* G = ws + 4608;       // 64*2800 = 179200 floats (stride-56 rows)
  float* sims = ws + 183808;  // 2304*3456 = 7,962,624 floats
  float* w1t = out;           // scratch in d_out; k_attn overwrites out last

  hipLaunchKernelGGL(k_tr, dim3(8, 16), dim3(256), 0, stream, W1, w1t);
  hipLaunchKernelGGL(k_gram, dim3(64), dim3(256), 0, stream, caps, G);
  hipLaunchKernelGGL(k_sims, dim3(486), dim3(256), 0, stream, imgs, caps, w1t,
                     sims);
  hipLaunchKernelGGL(k_unc, dim3(576), dim3(256), 0, stream, sims, imgs, b1,
                     W2, b2, unc, nrm);
  hipLaunchKernelGGL(k_attn, dim3(4096), dim3(512), 0, stream, sims, G, unc,
                     nrm, img_lens, cap_lens, imgs, caps, out);
}